// Round 1
// baseline (287.811 us; speedup 1.0000x reference)
//
#include <hip/hip_runtime.h>

#define DEV __device__ __forceinline__

typedef __attribute__((ext_vector_type(4))) float f32x4;
typedef __attribute__((ext_vector_type(8))) __bf16 bf16x8;

typedef __attribute__((address_space(1))) const uint32_t gu32;
typedef __attribute__((address_space(3))) uint32_t su32;

// async global->LDS, 16B per lane. LDS dest = wave-uniform base + lane*16.
DEV void gload16(const void* g, void* s) {
  __builtin_amdgcn_global_load_lds((gu32*)(uintptr_t)g,
                                   (su32*)(uint32_t)(uintptr_t)s, 16, 0, 0);
}

DEV ushort f2bf(float f) {
  unsigned u = __builtin_bit_cast(unsigned, f);
  u = (u + 0x7fffu + ((u >> 16) & 1u)) >> 16;
  return (ushort)u;
}

DEV bf16x8 lds8(const ushort* p) {
  return __builtin_bit_cast(bf16x8, *(const uint4*)(p));
}

// ---------------- fp32 -> bf16 convert ----------------
__global__ void cvt_bf16(const float* __restrict__ src, ushort* __restrict__ dst, int n4) {
  int i = blockIdx.x * blockDim.x + threadIdx.x;
  if (i >= n4) return;
  float4 v = ((const float4*)src)[i];
  ushort4 o;
  o.x = f2bf(v.x); o.y = f2bf(v.y); o.z = f2bf(v.z); o.w = f2bf(v.w);
  ((ushort4*)dst)[i] = o;
}

// ---------------- GEMM: C[M=4096,N=1024] = A[4096,1024] @ W[1024,1024]^T ----------------
// 128x128 tile, 4 waves (2x2), each wave 64x64 (4x4 frags), BK=32.
// LDS slot swizzle: logical k-slot g of row r lives at physical slot (g + (r>>1)) & 3.
template <int F32OUT>
DEV void gemm_core(const ushort* __restrict__ A, const ushort* __restrict__ W,
                   void* __restrict__ Cout, ushort* sA, ushort* sB) {
  const int tid = threadIdx.x;
  const int l = tid & 63, wv = tid >> 6;
  const int g = l >> 4, lan = l & 15;
  const int wr = wv >> 1, wc = wv & 1;
  const int brow = blockIdx.y * 128, bcol = blockIdx.x * 128;

  f32x4 acc[4][4] = {};

  for (int k0 = 0; k0 < 1024; k0 += 32) {
    __syncthreads();
#pragma unroll
    for (int i = 0; i < 2; ++i) {
      int n = i * 256 + wv * 64 + l;          // 16B chunk id, 0..511
      int row = n >> 2;                        // 4 chunks per 64B row
      int ss = n & 3;
      int gs = (ss - (row >> 1)) & 3;          // logical slot stored here
      gload16(A + (size_t)(brow + row) * 1024 + k0 + gs * 8,
              sA + (size_t)(i * 256 + wv * 64) * 8);
      gload16(W + (size_t)(bcol + row) * 1024 + k0 + gs * 8,
              sB + (size_t)(i * 256 + wv * 64) * 8);
    }
    __syncthreads();

    bf16x8 a[4], b[4];
#pragma unroll
    for (int fr = 0; fr < 4; ++fr) {
      int row = wr * 64 + fr * 16 + lan;
      a[fr] = lds8(sA + row * 32 + 8 * (((row >> 1) + g) & 3));
    }
#pragma unroll
    for (int fn = 0; fn < 4; ++fn) {
      int row = wc * 64 + fn * 16 + lan;
      b[fn] = lds8(sB + row * 32 + 8 * (((row >> 1) + g) & 3));
    }
#pragma unroll
    for (int fr = 0; fr < 4; ++fr)
#pragma unroll
      for (int fn = 0; fn < 4; ++fn)
        acc[fr][fn] = __builtin_amdgcn_mfma_f32_16x16x32_bf16(a[fr], b[fn], acc[fr][fn], 0, 0, 0);
  }

#pragma unroll
  for (int fr = 0; fr < 4; ++fr)
#pragma unroll
    for (int fn = 0; fn < 4; ++fn)
#pragma unroll
      for (int r = 0; r < 4; ++r) {
        int row = brow + wr * 64 + fr * 16 + g * 4 + r;
        int col = bcol + wc * 64 + fn * 16 + lan;
        if (F32OUT)
          ((float*)Cout)[(size_t)row * 1024 + col] = acc[fr][fn][r];
        else
          ((ushort*)Cout)[(size_t)row * 1024 + col] = f2bf(acc[fr][fn][r]);
      }
}

__global__ __launch_bounds__(256) void gemm_qkv(
    const ushort* __restrict__ X, const ushort* __restrict__ Wq,
    const ushort* __restrict__ Wk, const ushort* __restrict__ Wv,
    ushort* __restrict__ Q, ushort* __restrict__ K, ushort* __restrict__ V) {
  __shared__ __align__(16) ushort sA[4096];
  __shared__ __align__(16) ushort sB[4096];
  const ushort* W = blockIdx.z == 0 ? Wq : (blockIdx.z == 1 ? Wk : Wv);
  ushort* C = blockIdx.z == 0 ? Q : (blockIdx.z == 1 ? K : V);
  gemm_core<0>(X, W, (void*)C, sA, sB);
}

__global__ __launch_bounds__(256) void gemm_out(
    const ushort* __restrict__ AO, const ushort* __restrict__ Wo, float* __restrict__ C) {
  __shared__ __align__(16) ushort sA[4096];
  __shared__ __align__(16) ushort sB[4096];
  gemm_core<1>(AO, Wo, (void*)C, sA, sB);
}

// ---------------- causal flash attention ----------------
// grid: (S/128, B*H). block 256 = 4 waves; wave owns 32 q rows. KV tile 64, Hd=64.
__global__ __launch_bounds__(256) void attn_fwd(
    const ushort* __restrict__ Qm, const ushort* __restrict__ Km,
    const ushort* __restrict__ Vm, ushort* __restrict__ AO) {
  __shared__ __align__(16) ushort sK[64 * 64];   // [kv][d], XOR-swizzled slots
  __shared__ __align__(16) ushort sV[64 * 64];   // V^T: [d][kv], XOR-swizzled
  __shared__ __align__(16) ushort sP[4 * 32 * 64]; // per-wave P [32][64], swizzled

  const int tid = threadIdx.x;
  const int l = tid & 63, wv = tid >> 6;
  const int g = l >> 4, lan = l & 15;
  const int qt = blockIdx.x, bh = blockIdx.y;
  const int b = bh >> 4, h = bh & 15;
  const int q0 = qt * 128 + wv * 32;

  // Q fragments held in registers: [qr][kf]
  bf16x8 qf[2][2];
#pragma unroll
  for (int qr = 0; qr < 2; ++qr)
#pragma unroll
    for (int kf = 0; kf < 2; ++kf) {
      const ushort* p = Qm + (size_t)(b * 2048 + q0 + qr * 16 + lan) * 1024 + h * 64 + kf * 32 + g * 8;
      qf[qr][kf] = __builtin_bit_cast(bf16x8, *(const uint4*)p);
    }

  float mrun[2][4], lrun[2][4];
  f32x4 o[2][4];
#pragma unroll
  for (int qr = 0; qr < 2; ++qr)
#pragma unroll
    for (int r = 0; r < 4; ++r) { mrun[qr][r] = -1e30f; lrun[qr][r] = 0.f; }
#pragma unroll
  for (int qr = 0; qr < 2; ++qr)
#pragma unroll
    for (int of = 0; of < 4; ++of) o[qr][of] = (f32x4){0.f, 0.f, 0.f, 0.f};

  ushort* Pw = sP + wv * 2048;
  const int nkt = 2 * qt + 2;

  for (int kt = 0; kt < nkt; ++kt) {
    __syncthreads();
    // stage K tile [64][64] via global_load_lds; source pre-swizzled so that
    // physical slot s of row r holds logical slot s^(r&7).
#pragma unroll
    for (int i = 0; i < 2; ++i) {
      int n = (wv * 2 + i) * 64 + l;           // chunk 0..511, 8 chunks/row
      int row = n >> 3, ss = n & 7;
      int gs = ss ^ (row & 7);
      gload16(Km + (size_t)(b * 2048 + kt * 64 + row) * 1024 + h * 64 + gs * 8,
              sK + (size_t)(wv * 2 + i) * 512);
    }
    // stage V^T (reg transpose), same XOR swizzle on kv-slots
#pragma unroll
    for (int i = 0; i < 2; ++i) {
      int c = i * 256 + tid;                    // 0..511
      int kv = c >> 3, d0 = (c & 7) * 8;
      union { uint4 u; ushort s[8]; } raw;
      raw.u = *(const uint4*)(Vm + (size_t)(b * 2048 + kt * 64 + kv) * 1024 + h * 64 + d0);
#pragma unroll
      for (int j = 0; j < 8; ++j) {
        int d = d0 + j;
        sV[d * 64 + 8 * ((kv >> 3) ^ (d & 7)) + (kv & 7)] = raw.s[j];
      }
    }
    __syncthreads();

    // S = Q K^T  (A=Q frag, B=K frag: col=kv=lan, k=d contiguous)
    f32x4 sc[2][4];
#pragma unroll
    for (int qr = 0; qr < 2; ++qr)
#pragma unroll
      for (int kvf = 0; kvf < 4; ++kvf) {
        f32x4 acc = (f32x4){0.f, 0.f, 0.f, 0.f};
#pragma unroll
        for (int kf = 0; kf < 2; ++kf) {
          int row = kvf * 16 + lan;
          bf16x8 kb = lds8(sK + row * 64 + 8 * (((kf * 4 + g) ^ (row & 7))));
          acc = __builtin_amdgcn_mfma_f32_16x16x32_bf16(qf[qr][kf], kb, acc, 0, 0, 0);
        }
        sc[qr][kvf] = acc;
      }

    // V fragments for PV: B[k=kv][n=d] from V^T rows (d), kv contiguous
    bf16x8 vb[4][2];
#pragma unroll
    for (int of = 0; of < 4; ++of)
#pragma unroll
      for (int kf = 0; kf < 2; ++kf) {
        int row = of * 16 + lan;
        vb[of][kf] = lds8(sV + row * 64 + 8 * (((kf * 4 + g) ^ (row & 7))));
      }

#pragma unroll
    for (int qr = 0; qr < 2; ++qr) {
      // online softmax over this KV tile
#pragma unroll
      for (int r = 0; r < 4; ++r) {
        int qg = qt * 128 + wv * 32 + qr * 16 + g * 4 + r;
        float mx = -1e30f;
#pragma unroll
        for (int kvf = 0; kvf < 4; ++kvf) {
          int kvg = kt * 64 + kvf * 16 + lan;
          float v = sc[qr][kvf][r] * 0.125f;
          v = (kvg <= qg) ? v : -1e30f;
          sc[qr][kvf][r] = v;
          mx = fmaxf(mx, v);
        }
#pragma unroll
        for (int off = 1; off < 16; off <<= 1) mx = fmaxf(mx, __shfl_xor(mx, off));
        float mnew = fmaxf(mrun[qr][r], mx);
        float alpha = __expf(mrun[qr][r] - mnew);
        mrun[qr][r] = mnew;
        float rs = 0.f;
#pragma unroll
        for (int kvf = 0; kvf < 4; ++kvf) {
          float p = __expf(sc[qr][kvf][r] - mnew);
          sc[qr][kvf][r] = p;
          rs += p;
        }
#pragma unroll
        for (int off = 1; off < 16; off <<= 1) rs += __shfl_xor(rs, off);
        lrun[qr][r] = lrun[qr][r] * alpha + rs;
#pragma unroll
        for (int of = 0; of < 4; ++of) o[qr][of][r] *= alpha;
      }
      // write P tile (C-layout -> swizzled LDS)
#pragma unroll
      for (int kvf = 0; kvf < 4; ++kvf)
#pragma unroll
        for (int r = 0; r < 4; ++r) {
          int q = qr * 16 + g * 4 + r;
          int kv = kvf * 16 + lan;
          Pw[q * 64 + 8 * ((kv >> 3) ^ (q & 7)) + (kv & 7)] = f2bf(sc[qr][kvf][r]);
        }
      // O += P V
#pragma unroll
      for (int kf = 0; kf < 2; ++kf) {
        int q = qr * 16 + lan;
        bf16x8 pa = lds8(Pw + q * 64 + 8 * (((kf * 4 + g) ^ (q & 7))));
#pragma unroll
        for (int of = 0; of < 4; ++of)
          o[qr][of] = __builtin_amdgcn_mfma_f32_16x16x32_bf16(pa, vb[of][kf], o[qr][of], 0, 0, 0);
      }
    }
  }

  // epilogue: divide by l and store bf16
#pragma unroll
  for (int qr = 0; qr < 2; ++qr)
#pragma unroll
    for (int r = 0; r < 4; ++r) {
      float inv = 1.0f / lrun[qr][r];
#pragma unroll
      for (int of = 0; of < 4; ++of) {
        int grow = q0 + qr * 16 + g * 4 + r;
        AO[(size_t)(b * 2048 + grow) * 1024 + h * 64 + of * 16 + lan] = f2bf(o[qr][of][r] * inv);
      }
    }
}

// ---------------- launch ----------------
extern "C" void kernel_launch(void* const* d_in, const int* in_sizes, int n_in,
                              void* d_out, int out_size, void* d_ws, size_t ws_size,
                              hipStream_t stream) {
  const float* x  = (const float*)d_in[0];
  const float* wq = (const float*)d_in[1];
  const float* wk = (const float*)d_in[2];
  const float* wv = (const float*)d_in[3];
  const float* wo = (const float*)d_in[4];
  float* out = (float*)d_out;

  char* ws = (char*)d_ws;
  const size_t MB = 1ull << 20;
  ushort* xb  = (ushort*)(ws + 0);        // 8 MB  [4096][1024]
  ushort* wqb = (ushort*)(ws + 8 * MB);   // 2 MB
  ushort* wkb = (ushort*)(ws + 10 * MB);
  ushort* wvb = (ushort*)(ws + 12 * MB);
  ushort* wob = (ushort*)(ws + 14 * MB);
  ushort* Q   = (ushort*)(ws + 16 * MB);  // 8 MB each
  ushort* K   = (ushort*)(ws + 24 * MB);
  ushort* V   = (ushort*)(ws + 32 * MB);
  ushort* AO  = (ushort*)(ws + 40 * MB);

  cvt_bf16<<<4096, 256, 0, stream>>>(x, xb, 1048576);
  cvt_bf16<<<1024, 256, 0, stream>>>(wq, wqb, 262144);
  cvt_bf16<<<1024, 256, 0, stream>>>(wk, wkb, 262144);
  cvt_bf16<<<1024, 256, 0, stream>>>(wv, wvb, 262144);
  cvt_bf16<<<1024, 256, 0, stream>>>(wo, wob, 262144);

  gemm_qkv<<<dim3(8, 32, 3), 256, 0, stream>>>(xb, wqb, wkb, wvb, Q, K, V);
  attn_fwd<<<dim3(16, 32), 256, 0, stream>>>(Q, K, V, AO);
  gemm_out<<<dim3(8, 32), 256, 0, stream>>>(AO, wob, out);
}

// Round 2
// 198.264 us; speedup vs baseline: 1.4517x; 1.4517x over previous
//
#include <hip/hip_runtime.h>

#define DEV __device__ __forceinline__

typedef __attribute__((ext_vector_type(4))) float f32x4;
typedef __attribute__((ext_vector_type(8))) __bf16 bf16x8;

typedef __attribute__((address_space(1))) const uint32_t gu32;
typedef __attribute__((address_space(3))) uint32_t su32;

// async global->LDS, 16B per lane. LDS dest = wave-uniform base + lane*16.
DEV void gload16(const void* g, void* s) {
  __builtin_amdgcn_global_load_lds((gu32*)(uintptr_t)g,
                                   (su32*)(uint32_t)(uintptr_t)s, 16, 0, 0);
}

DEV ushort f2bf(float f) {
  unsigned u = __builtin_bit_cast(unsigned, f);
  u = (u + 0x7fffu + ((u >> 16) & 1u)) >> 16;
  return (ushort)u;
}

DEV bf16x8 lds8(const ushort* p) {
  return __builtin_bit_cast(bf16x8, *(const uint4*)(p));
}

// ---------------- fp32 -> bf16 convert ----------------
__global__ void cvt_bf16(const float* __restrict__ src, ushort* __restrict__ dst, int n4) {
  int i = blockIdx.x * blockDim.x + threadIdx.x;
  if (i >= n4) return;
  float4 v = ((const float4*)src)[i];
  ushort4 o;
  o.x = f2bf(v.x); o.y = f2bf(v.y); o.z = f2bf(v.z); o.w = f2bf(v.w);
  ((ushort4*)dst)[i] = o;
}

// ---------------- GEMM: C[M=4096,N=1024] = A[4096,1024] @ W[1024,1024]^T ----------------
// 128x128 tile, 4 waves (2x2), each wave 64x64 (4x4 frags), BK=32.
template <int F32OUT>
DEV void gemm_core(const ushort* __restrict__ A, const ushort* __restrict__ W,
                   void* __restrict__ Cout, ushort* sA, ushort* sB) {
  const int tid = threadIdx.x;
  const int l = tid & 63, wv = tid >> 6;
  const int g = l >> 4, lan = l & 15;
  const int wr = wv >> 1, wc = wv & 1;
  const int brow = blockIdx.y * 128, bcol = blockIdx.x * 128;

  f32x4 acc[4][4] = {};

  for (int k0 = 0; k0 < 1024; k0 += 32) {
    __syncthreads();
#pragma unroll
    for (int i = 0; i < 2; ++i) {
      int n = i * 256 + wv * 64 + l;
      int row = n >> 2;
      int ss = n & 3;
      int gs = (ss - (row >> 1)) & 3;
      gload16(A + (size_t)(brow + row) * 1024 + k0 + gs * 8,
              sA + (size_t)(i * 256 + wv * 64) * 8);
      gload16(W + (size_t)(bcol + row) * 1024 + k0 + gs * 8,
              sB + (size_t)(i * 256 + wv * 64) * 8);
    }
    __syncthreads();

    bf16x8 a[4], b[4];
#pragma unroll
    for (int fr = 0; fr < 4; ++fr) {
      int row = wr * 64 + fr * 16 + lan;
      a[fr] = lds8(sA + row * 32 + 8 * (((row >> 1) + g) & 3));
    }
#pragma unroll
    for (int fn = 0; fn < 4; ++fn) {
      int row = wc * 64 + fn * 16 + lan;
      b[fn] = lds8(sB + row * 32 + 8 * (((row >> 1) + g) & 3));
    }
#pragma unroll
    for (int fr = 0; fr < 4; ++fr)
#pragma unroll
      for (int fn = 0; fn < 4; ++fn)
        acc[fr][fn] = __builtin_amdgcn_mfma_f32_16x16x32_bf16(a[fr], b[fn], acc[fr][fn], 0, 0, 0);
  }

#pragma unroll
  for (int fr = 0; fr < 4; ++fr)
#pragma unroll
    for (int fn = 0; fn < 4; ++fn)
#pragma unroll
      for (int r = 0; r < 4; ++r) {
        int row = brow + wr * 64 + fr * 16 + g * 4 + r;
        int col = bcol + wc * 64 + fn * 16 + lan;
        if (F32OUT)
          ((float*)Cout)[(size_t)row * 1024 + col] = acc[fr][fn][r];
        else
          ((ushort*)Cout)[(size_t)row * 1024 + col] = f2bf(acc[fr][fn][r]);
      }
}

__global__ __launch_bounds__(256) void gemm_qkv(
    const ushort* __restrict__ X, const ushort* __restrict__ Wq,
    const ushort* __restrict__ Wk, const ushort* __restrict__ Wv,
    ushort* __restrict__ Q, ushort* __restrict__ K, ushort* __restrict__ V) {
  __shared__ __align__(16) ushort sA[4096];
  __shared__ __align__(16) ushort sB[4096];
  const ushort* W = blockIdx.z == 0 ? Wq : (blockIdx.z == 1 ? Wk : Wv);
  ushort* C = blockIdx.z == 0 ? Q : (blockIdx.z == 1 ? K : V);
  gemm_core<0>(X, W, (void*)C, sA, sB);
}

__global__ __launch_bounds__(256) void gemm_out(
    const ushort* __restrict__ AO, const ushort* __restrict__ Wo, float* __restrict__ C) {
  __shared__ __align__(16) ushort sA[4096];
  __shared__ __align__(16) ushort sB[4096];
  gemm_core<1>(AO, Wo, (void*)C, sA, sB);
}

// ---------------- V transpose: V[b,s,h*64+d] -> Vt[bh, d, s] ----------------
// grid (32 s-tiles, 32 bh), 256 threads. 64x64 tile via swizzled LDS.
__global__ __launch_bounds__(256) void vt_kernel(const ushort* __restrict__ V,
                                                 ushort* __restrict__ Vt) {
  __shared__ __align__(16) ushort T[64 * 64];
  const int tid = threadIdx.x;
  const int stile = blockIdx.x, bh = blockIdx.y;
  const int b = bh >> 4, h = bh & 15;

#pragma unroll
  for (int i = 0; i < 2; ++i) {
    int m = i * 256 + tid;
    int s = m >> 3, dc = m & 7;
    uint4 v = *(const uint4*)(V + (size_t)(b * 2048 + stile * 64 + s) * 1024 + h * 64 + dc * 8);
    // 16B-chunk swizzle keyed on s>>3 (so out-reads spread banks)
    *(uint4*)(T + s * 64 + ((8 * dc) ^ (((s >> 3) & 7) << 3))) = v;
  }
  __syncthreads();

#pragma unroll
  for (int i = 0; i < 2; ++i) {
    int m = i * 256 + tid;
    int d = m >> 3, sb = m & 7;
    ushort tmp[8];
#pragma unroll
    for (int e = 0; e < 8; ++e)
      tmp[e] = T[(sb * 8 + e) * 64 + (d ^ (sb << 3))];
    uint4 o;
    o.x = (uint)tmp[0] | ((uint)tmp[1] << 16);
    o.y = (uint)tmp[2] | ((uint)tmp[3] << 16);
    o.z = (uint)tmp[4] | ((uint)tmp[5] << 16);
    o.w = (uint)tmp[6] | ((uint)tmp[7] << 16);
    *(uint4*)(Vt + ((size_t)bh * 64 + d) * 2048 + stile * 64 + sb * 8) = o;
  }
}

// ---------------- causal flash attention ----------------
// 1024 blocks (heavy q-tiles first), 4 waves x 16 q-rows, KV tile 64, Hd=64.
// Swapped QK^T: lane owns q-row = lan; per-lane online softmax.
__global__ __launch_bounds__(256) void attn_fwd(
    const ushort* __restrict__ Qm, const ushort* __restrict__ Km,
    const ushort* __restrict__ Vt, ushort* __restrict__ AO) {
  __shared__ __align__(16) ushort sK[64 * 64];   // [kv][d], XOR slot swizzle
  __shared__ __align__(16) ushort sV[64 * 64];   // Vt tile [d][kv], XOR slot swizzle
  __shared__ __align__(16) ushort sP[4 * 16 * 64]; // per-wave P [16 q][64 kv], swizzled

  const int tid = threadIdx.x;
  const int l = tid & 63, wv = tid >> 6;
  const int g = l >> 4, lan = l & 15;
  const int bid = blockIdx.x;
  const int rank = bid >> 5, bh = bid & 31;
  const int qt = 31 - rank;                       // heaviest first
  const int b = bh >> 4, h = bh & 15;
  const int q0 = qt * 64 + wv * 16;
  const int qg = q0 + lan;                        // this lane's q row

  // Q fragments (B-operand of swapped QK^T): lane holds Q[q=q0+lan][d contiguous 8]
  bf16x8 qf[2];
#pragma unroll
  for (int kf = 0; kf < 2; ++kf)
    qf[kf] = __builtin_bit_cast(bf16x8,
        *(const uint4*)(Qm + (size_t)(b * 2048 + qg) * 1024 + h * 64 + kf * 32 + g * 8));

  float mrun = -1e30f, lrun = 0.f;
  f32x4 o[4];
#pragma unroll
  for (int of = 0; of < 4; ++of) o[of] = (f32x4){0.f, 0.f, 0.f, 0.f};

  ushort* Pw = sP + wv * 1024;
  const int nkt = qt + 1;

  for (int kt = 0; kt < nkt; ++kt) {
    __syncthreads();
    // stage K [64 kv][64 d] and Vt [64 d][64 kv]; phys slot s holds logical s^(row&7)
#pragma unroll
    for (int i = 0; i < 2; ++i) {
      int n = i * 256 + wv * 64 + l;
      int row = n >> 3, ss = n & 7, gs = ss ^ (row & 7);
      gload16(Km + (size_t)(b * 2048 + kt * 64 + row) * 1024 + h * 64 + gs * 8,
              sK + (size_t)(i * 256 + wv * 64) * 8);
      gload16(Vt + ((size_t)bh * 64 + row) * 2048 + kt * 64 + gs * 8,
              sV + (size_t)(i * 256 + wv * 64) * 8);
    }
    __syncthreads();

    // S^T = K Q^T : sc[kvf] rows = kv, cols = q
    f32x4 sc[4];
    __builtin_amdgcn_s_setprio(1);
#pragma unroll
    for (int kvf = 0; kvf < 4; ++kvf) {
      f32x4 acc = (f32x4){0.f, 0.f, 0.f, 0.f};
#pragma unroll
      for (int kf = 0; kf < 2; ++kf) {
        int row = kvf * 16 + lan;
        bf16x8 kb = lds8(sK + row * 64 + 8 * ((kf * 4 + g) ^ (row & 7)));
        acc = __builtin_amdgcn_mfma_f32_16x16x32_bf16(kb, qf[kf], acc, 0, 0, 0);
      }
      sc[kvf] = acc;
    }
    __builtin_amdgcn_s_setprio(0);

    // per-lane online softmax: lane has 16 scores for q=qg, kv = kt*64+kvf*16+4g+r
    float mx = -1e30f;
#pragma unroll
    for (int kvf = 0; kvf < 4; ++kvf)
#pragma unroll
      for (int r = 0; r < 4; ++r) {
        int kvg = kt * 64 + kvf * 16 + 4 * g + r;
        float v = sc[kvf][r] * 0.125f;
        v = (kvg <= qg) ? v : -1e30f;
        sc[kvf][r] = v;
        mx = fmaxf(mx, v);
      }
    mx = fmaxf(mx, __shfl_xor(mx, 16));
    mx = fmaxf(mx, __shfl_xor(mx, 32));
    float mnew = fmaxf(mrun, mx);
    float alpha = __expf(mrun - mnew);
    mrun = mnew;
    float rs = 0.f;
#pragma unroll
    for (int kvf = 0; kvf < 4; ++kvf)
#pragma unroll
      for (int r = 0; r < 4; ++r) {
        float p = __expf(sc[kvf][r] - mnew);
        sc[kvf][r] = p;
        rs += p;
      }
    rs += __shfl_xor(rs, 16);
    rs += __shfl_xor(rs, 32);
    lrun = lrun * alpha + rs;

    // write P: lane -> row q=lan, 4 consecutive kv per b64, 16B-XOR swizzle
#pragma unroll
    for (int kvf = 0; kvf < 4; ++kvf) {
      ushort4 pk;
      pk.x = f2bf(sc[kvf][0]); pk.y = f2bf(sc[kvf][1]);
      pk.z = f2bf(sc[kvf][2]); pk.w = f2bf(sc[kvf][3]);
      *(ushort4*)(Pw + lan * 64 + ((16 * kvf + 4 * g) ^ ((lan & 7) << 3))) = pk;
    }

    // rescale O (rows = q = 4g+r): fetch alpha for each row from its owner lane
    float al[4];
#pragma unroll
    for (int r = 0; r < 4; ++r) al[r] = __shfl(alpha, g * 4 + r);
#pragma unroll
    for (int of = 0; of < 4; ++of)
#pragma unroll
      for (int r = 0; r < 4; ++r) o[of][r] *= al[r];

    // P A-frags: lane reads its own row, kv = kf*32 + g*8 .. +7
    bf16x8 pa[2];
#pragma unroll
    for (int kf = 0; kf < 2; ++kf)
      pa[kf] = lds8(Pw + lan * 64 + ((32 * kf + 8 * g) ^ ((lan & 7) << 3)));

    __builtin_amdgcn_s_setprio(1);
#pragma unroll
    for (int of = 0; of < 4; ++of) {
#pragma unroll
      for (int kf = 0; kf < 2; ++kf) {
        int row = of * 16 + lan;
        bf16x8 vb = lds8(sV + row * 64 + 8 * ((kf * 4 + g) ^ (row & 7)));
        o[of] = __builtin_amdgcn_mfma_f32_16x16x32_bf16(pa[kf], vb, o[of], 0, 0, 0);
      }
    }
    __builtin_amdgcn_s_setprio(0);
  }

  // epilogue: rows q = 4g+r, cols d = of*16+lan
#pragma unroll
  for (int r = 0; r < 4; ++r) {
    float il = 1.0f / __shfl(lrun, g * 4 + r);
#pragma unroll
    for (int of = 0; of < 4; ++of) {
      int grow = qt * 64 + wv * 16 + g * 4 + r;
      AO[(size_t)(b * 2048 + grow) * 1024 + h * 64 + of * 16 + lan] = f2bf(o[of][r] * il);
    }
  }
}

// ---------------- launch ----------------
extern "C" void kernel_launch(void* const* d_in, const int* in_sizes, int n_in,
                              void* d_out, int out_size, void* d_ws, size_t ws_size,
                              hipStream_t stream) {
  const float* x  = (const float*)d_in[0];
  const float* wq = (const float*)d_in[1];
  const float* wk = (const float*)d_in[2];
  const float* wv = (const float*)d_in[3];
  const float* wo = (const float*)d_in[4];
  float* out = (float*)d_out;

  char* ws = (char*)d_ws;
  const size_t MB = 1ull << 20;
  ushort* xb  = (ushort*)(ws + 0);        // 8 MB; reused as Vt after gemm_qkv
  ushort* wqb = (ushort*)(ws + 8 * MB);
  ushort* wkb = (ushort*)(ws + 10 * MB);
  ushort* wvb = (ushort*)(ws + 12 * MB);
  ushort* wob = (ushort*)(ws + 14 * MB);
  ushort* Q   = (ushort*)(ws + 16 * MB);
  ushort* K   = (ushort*)(ws + 24 * MB);
  ushort* V   = (ushort*)(ws + 32 * MB);
  ushort* AO  = (ushort*)(ws + 40 * MB);
  ushort* Vt  = (ushort*)(ws + 0);        // overwrites xb (dead after gemm_qkv)

  cvt_bf16<<<4096, 256, 0, stream>>>(x, xb, 1048576);
  cvt_bf16<<<1024, 256, 0, stream>>>(wq, wqb, 262144);
  cvt_bf16<<<1024, 256, 0, stream>>>(wk, wkb, 262144);
  cvt_bf16<<<1024, 256, 0, stream>>>(wv, wvb, 262144);
  cvt_bf16<<<1024, 256, 0, stream>>>(wo, wob, 262144);

  gemm_qkv<<<dim3(8, 32, 3), 256, 0, stream>>>(xb, wqb, wkb, wvb, Q, K, V);
  vt_kernel<<<dim3(32, 32), 256, 0, stream>>>(V, Vt);
  attn_fwd<<<1024, 256, 0, stream>>>(Q, K, Vt, AO);
  gemm_out<<<dim3(8, 32), 256, 0, stream>>>(AO, wob, out);
}

// Round 3
// 184.358 us; speedup vs baseline: 1.5612x; 1.0754x over previous
//
#include <hip/hip_runtime.h>

#define DEV __device__ __forceinline__

typedef __attribute__((ext_vector_type(4))) float f32x4;
typedef __attribute__((ext_vector_type(8))) __bf16 bf16x8;

typedef __attribute__((address_space(1))) const uint32_t gu32;
typedef __attribute__((address_space(3))) uint32_t su32;

// async global->LDS, 16B per lane. LDS dest = wave-uniform base + lane*16.
DEV void gload16(const void* g, void* s) {
  __builtin_amdgcn_global_load_lds((gu32*)(uintptr_t)g,
                                   (su32*)(uint32_t)(uintptr_t)s, 16, 0, 0);
}

DEV ushort bfbits(float f) { return __builtin_bit_cast(ushort, (__bf16)f); }

DEV bf16x8 lds8(const ushort* p) {
  return __builtin_bit_cast(bf16x8, *(const uint4*)(p));
}

DEV void vmcnt0bar() {
  asm volatile("s_waitcnt vmcnt(0)" ::: "memory");
  __builtin_amdgcn_s_barrier();
}

// ---------------- fused fp32 -> bf16 convert (x + 4 weights; wq pre-scaled) ----------------
// scores/8 in exp2 domain: fold 0.125*log2(e) into Wq.
__global__ void cvt_all(const float* __restrict__ x, const float* __restrict__ wq,
                        const float* __restrict__ wk, const float* __restrict__ wv,
                        const float* __restrict__ wo, ushort* __restrict__ xb,
                        ushort* __restrict__ wb) {
  int i = blockIdx.x * blockDim.x + threadIdx.x;  // float4 id; total 2,097,152
  const float* src; ushort* dst; float scl = 1.0f; int j;
  if (i < 1048576) { src = x; dst = xb; j = i; }
  else {
    int t = (i - 1048576) >> 18;
    j = (i - 1048576) & 262143;
    src = t == 0 ? wq : (t == 1 ? wk : (t == 2 ? wv : wo));
    dst = wb + t * 1048576;
    if (t == 0) scl = 0.18033688011f;  // 0.125 * log2(e)
  }
  float4 v = ((const float4*)src)[j];
  ushort4 o;
  o.x = bfbits(v.x * scl); o.y = bfbits(v.y * scl);
  o.z = bfbits(v.z * scl); o.w = bfbits(v.w * scl);
  ((ushort4*)dst)[j] = o;
}

// ---------------- 2-phase pipelined GEMM: C[M,N] = A[M,1024] @ W[N,1024]^T ----------------
// Block tile 128 x (NFR*32). 4 waves (2x2); wave = 64 x (NFR*16); BK=32; double-buffered LDS.
template <int NFR, int F32OUT>
DEV void gemm_core(const ushort* __restrict__ A, const ushort* __restrict__ W,
                   void* __restrict__ Cout, ushort* sA, ushort* sB) {
  const int tid = threadIdx.x;
  const int l = tid & 63, wv = tid >> 6;
  const int g = l >> 4, lan = l & 15;
  const int wr = wv >> 1, wc = wv & 1;
  const int brow = blockIdx.y * 128, bcol = blockIdx.x * (NFR * 32);
  const int ASZ = 128 * 32, BSZ = NFR * 32 * 32;

  f32x4 acc[4][NFR] = {};

  auto stage = [&](int buf, int k0) {
    ushort* dA = sA + buf * ASZ;
    ushort* dB = sB + buf * BSZ;
#pragma unroll
    for (int i = 0; i < 2; ++i) {
      int n = i * 256 + wv * 64 + l;
      int row = n >> 2, ss = n & 3, gs = (ss - (row >> 1)) & 3;
      gload16(A + (size_t)(brow + row) * 1024 + k0 + gs * 8,
              dA + (i * 256 + wv * 64) * 8);
    }
#pragma unroll
    for (int i = 0; i < NFR / 2; ++i) {
      int n = i * 256 + wv * 64 + l;
      int row = n >> 2, ss = n & 3, gs = (ss - (row >> 1)) & 3;
      gload16(W + (size_t)(bcol + row) * 1024 + k0 + gs * 8,
              dB + (i * 256 + wv * 64) * 8);
    }
  };

  auto compute = [&](int buf) {
    const ushort* cA = sA + buf * ASZ;
    const ushort* cB = sB + buf * BSZ;
    bf16x8 a[4], b[NFR];
#pragma unroll
    for (int fr = 0; fr < 4; ++fr) {
      int row = wr * 64 + fr * 16 + lan;
      a[fr] = lds8(cA + row * 32 + 8 * (((row >> 1) + g) & 3));
    }
#pragma unroll
    for (int fn = 0; fn < NFR; ++fn) {
      int row = wc * (NFR * 16) + fn * 16 + lan;
      b[fn] = lds8(cB + row * 32 + 8 * (((row >> 1) + g) & 3));
    }
    __builtin_amdgcn_s_setprio(1);
#pragma unroll
    for (int fr = 0; fr < 4; ++fr)
#pragma unroll
      for (int fn = 0; fn < NFR; ++fn)
        acc[fr][fn] = __builtin_amdgcn_mfma_f32_16x16x32_bf16(a[fr], b[fn], acc[fr][fn], 0, 0, 0);
    __builtin_amdgcn_s_setprio(0);
  };

  stage(0, 0);
  vmcnt0bar();
#pragma unroll 1
  for (int t = 0; t < 15; ++t) {
    stage(1, (2 * t + 1) * 32); compute(0); vmcnt0bar();
    stage(0, (2 * t + 2) * 32); compute(1); vmcnt0bar();
  }
  stage(1, 31 * 32); compute(0); vmcnt0bar();
  compute(1);

#pragma unroll
  for (int fr = 0; fr < 4; ++fr)
#pragma unroll
    for (int fn = 0; fn < NFR; ++fn)
#pragma unroll
      for (int r = 0; r < 4; ++r) {
        int row = brow + wr * 64 + fr * 16 + g * 4 + r;
        int col = bcol + wc * (NFR * 16) + fn * 16 + lan;
        if (F32OUT)
          ((float*)Cout)[(size_t)row * 1024 + col] = acc[fr][fn][r];
        else
          ((ushort*)Cout)[(size_t)row * 1024 + col] = bfbits(acc[fr][fn][r]);
      }
}

__global__ __launch_bounds__(256) void gemm_qkv(
    const ushort* __restrict__ X, const ushort* __restrict__ Wb,
    ushort* __restrict__ Q, ushort* __restrict__ K, ushort* __restrict__ V) {
  __shared__ __align__(16) ushort sA[2 * 128 * 32];
  __shared__ __align__(16) ushort sB[2 * 128 * 32];
  const ushort* W = Wb + (size_t)blockIdx.z * 1048576;
  ushort* C = blockIdx.z == 0 ? Q : (blockIdx.z == 1 ? K : V);
  gemm_core<4, 0>(X, W, (void*)C, sA, sB);
}

__global__ __launch_bounds__(256) void gemm_out(
    const ushort* __restrict__ AO, const ushort* __restrict__ Wo, float* __restrict__ C) {
  __shared__ __align__(16) ushort sA[2 * 128 * 32];
  __shared__ __align__(16) ushort sB[2 * 64 * 32];
  gemm_core<2, 1>(AO, Wo, (void*)C, sA, sB);
}

// ---------------- V transpose: V[b,s,h*64+d] -> Vt[bh, d, s] ----------------
__global__ __launch_bounds__(256) void vt_kernel(const ushort* __restrict__ V,
                                                 ushort* __restrict__ Vt) {
  __shared__ __align__(16) ushort T[64 * 64];
  const int tid = threadIdx.x;
  const int stile = blockIdx.x, bh = blockIdx.y;
  const int b = bh >> 4, h = bh & 15;

#pragma unroll
  for (int i = 0; i < 2; ++i) {
    int m = i * 256 + tid;
    int s = m >> 3, dc = m & 7;
    uint4 v = *(const uint4*)(V + (size_t)(b * 2048 + stile * 64 + s) * 1024 + h * 64 + dc * 8);
    *(uint4*)(T + s * 64 + ((8 * dc) ^ (((s >> 3) & 7) << 3))) = v;
  }
  __syncthreads();

#pragma unroll
  for (int i = 0; i < 2; ++i) {
    int m = i * 256 + tid;
    int d = m >> 3, sb = m & 7;
    ushort tmp[8];
#pragma unroll
    for (int e = 0; e < 8; ++e)
      tmp[e] = T[(sb * 8 + e) * 64 + (d ^ (sb << 3))];
    uint4 o;
    o.x = (uint)tmp[0] | ((uint)tmp[1] << 16);
    o.y = (uint)tmp[2] | ((uint)tmp[3] << 16);
    o.z = (uint)tmp[4] | ((uint)tmp[5] << 16);
    o.w = (uint)tmp[6] | ((uint)tmp[7] << 16);
    *(uint4*)(Vt + ((size_t)bh * 64 + d) * 2048 + stile * 64 + sb * 8) = o;
  }
}

// ---------------- causal flash attention (exp2 domain; Q pre-scaled via Wq) ----------------
// 1024 blocks heavy-first; 4 waves x 16 q-rows; KV tile 64 double-buffered; Hd=64.
__global__ __launch_bounds__(256) void attn_fwd(
    const ushort* __restrict__ Qm, const ushort* __restrict__ Km,
    const ushort* __restrict__ Vt, ushort* __restrict__ AO) {
  __shared__ __align__(16) ushort sK[2][64 * 64];
  __shared__ __align__(16) ushort sV[2][64 * 64];
  __shared__ __align__(16) ushort sP[4 * 16 * 64];

  const int tid = threadIdx.x;
  const int l = tid & 63, wv = tid >> 6;
  const int g = l >> 4, lan = l & 15;
  const int bid = blockIdx.x;
  const int rank = bid >> 5, bh = bid & 31;
  const int qt = 31 - rank;
  const int b = bh >> 4, h = bh & 15;
  const int q0 = qt * 64 + wv * 16;
  const int qg = q0 + lan;

  bf16x8 qf[2];
#pragma unroll
  for (int kf = 0; kf < 2; ++kf)
    qf[kf] = __builtin_bit_cast(bf16x8,
        *(const uint4*)(Qm + (size_t)(b * 2048 + qg) * 1024 + h * 64 + kf * 32 + g * 8));

  float mrun = -1e30f, lrun = 0.f;
  f32x4 o[4];
#pragma unroll
  for (int of = 0; of < 4; ++of) o[of] = (f32x4){0.f, 0.f, 0.f, 0.f};

  ushort* Pw = sP + wv * 1024;
  const int nkt = qt + 1;

  auto stagekv = [&](int buf, int kt) {
#pragma unroll
    for (int i = 0; i < 2; ++i) {
      int n = i * 256 + wv * 64 + l;
      int row = n >> 3, ss = n & 7, gs = ss ^ (row & 7);
      gload16(Km + (size_t)(b * 2048 + kt * 64 + row) * 1024 + h * 64 + gs * 8,
              sK[buf] + (i * 256 + wv * 64) * 8);
      gload16(Vt + ((size_t)bh * 64 + row) * 2048 + kt * 64 + gs * 8,
              sV[buf] + (i * 256 + wv * 64) * 8);
    }
  };

  stagekv(0, 0);
  vmcnt0bar();

#pragma unroll 1
  for (int kt = 0; kt < nkt; ++kt) {
    const int buf = kt & 1;
    if (kt + 1 < nkt) stagekv(buf ^ 1, kt + 1);

    // S^T = K Q^T (already in exp2 domain)
    f32x4 sc[4];
    __builtin_amdgcn_s_setprio(1);
#pragma unroll
    for (int kvf = 0; kvf < 4; ++kvf) {
      f32x4 a2 = (f32x4){0.f, 0.f, 0.f, 0.f};
#pragma unroll
      for (int kf = 0; kf < 2; ++kf) {
        int row = kvf * 16 + lan;
        bf16x8 kb = lds8(sK[buf] + row * 64 + 8 * ((kf * 4 + g) ^ (row & 7)));
        a2 = __builtin_amdgcn_mfma_f32_16x16x32_bf16(kb, qf[kf], a2, 0, 0, 0);
      }
      sc[kvf] = a2;
    }
    __builtin_amdgcn_s_setprio(0);

    // mask only the diagonal tile
    if (kt == qt) {
#pragma unroll
      for (int kvf = 0; kvf < 4; ++kvf)
#pragma unroll
        for (int r = 0; r < 4; ++r) {
          int kvg = kt * 64 + kvf * 16 + 4 * g + r;
          sc[kvf][r] = (kvg <= qg) ? sc[kvf][r] : -1e30f;
        }
    }

    float mx = sc[0][0];
#pragma unroll
    for (int kvf = 0; kvf < 4; ++kvf)
#pragma unroll
      for (int r = 0; r < 4; ++r) mx = fmaxf(mx, sc[kvf][r]);
    mx = fmaxf(mx, __shfl_xor(mx, 16));
    mx = fmaxf(mx, __shfl_xor(mx, 32));

    const bool noresc = __all(mx <= mrun + 8.0f);   // T13 defer-max, THR=8 (log2)
    const float mnew = noresc ? mrun : fmaxf(mrun, mx);

    float rs = 0.f;
#pragma unroll
    for (int kvf = 0; kvf < 4; ++kvf)
#pragma unroll
      for (int r = 0; r < 4; ++r) {
        float p = __builtin_exp2f(sc[kvf][r] - mnew);
        sc[kvf][r] = p;
        rs += p;
      }
    rs += __shfl_xor(rs, 16);
    rs += __shfl_xor(rs, 32);

    if (noresc) {
      lrun += rs;
    } else {
      float alpha = __builtin_exp2f(mrun - mnew);
      mrun = mnew;
      lrun = lrun * alpha + rs;
      float al[4];
#pragma unroll
      for (int r = 0; r < 4; ++r) al[r] = __shfl(alpha, g * 4 + r);
#pragma unroll
      for (int of = 0; of < 4; ++of)
#pragma unroll
        for (int r = 0; r < 4; ++r) o[of][r] *= al[r];
    }

    // write P tile (packed, swizzled)
#pragma unroll
    for (int kvf = 0; kvf < 4; ++kvf) {
      ushort4 pk;
      pk.x = bfbits(sc[kvf][0]); pk.y = bfbits(sc[kvf][1]);
      pk.z = bfbits(sc[kvf][2]); pk.w = bfbits(sc[kvf][3]);
      *(ushort4*)(Pw + lan * 64 + ((16 * kvf + 4 * g) ^ ((lan & 7) << 3))) = pk;
    }
    bf16x8 pa[2];
#pragma unroll
    for (int kf = 0; kf < 2; ++kf)
      pa[kf] = lds8(Pw + lan * 64 + ((32 * kf + 8 * g) ^ ((lan & 7) << 3)));

    __builtin_amdgcn_s_setprio(1);
#pragma unroll
    for (int of = 0; of < 4; ++of)
#pragma unroll
      for (int kf = 0; kf < 2; ++kf) {
        int row = of * 16 + lan;
        bf16x8 vb = lds8(sV[buf] + row * 64 + 8 * ((kf * 4 + g) ^ (row & 7)));
        o[of] = __builtin_amdgcn_mfma_f32_16x16x32_bf16(pa[kf], vb, o[of], 0, 0, 0);
      }
    __builtin_amdgcn_s_setprio(0);

    vmcnt0bar();
  }

#pragma unroll
  for (int r = 0; r < 4; ++r) {
    float il = 1.0f / __shfl(lrun, g * 4 + r);
#pragma unroll
    for (int of = 0; of < 4; ++of) {
      int grow = qt * 64 + wv * 16 + g * 4 + r;
      AO[(size_t)(b * 2048 + grow) * 1024 + h * 64 + of * 16 + lan] = bfbits(o[of][r] * il);
    }
  }
}

// ---------------- launch ----------------
extern "C" void kernel_launch(void* const* d_in, const int* in_sizes, int n_in,
                              void* d_out, int out_size, void* d_ws, size_t ws_size,
                              hipStream_t stream) {
  const float* x  = (const float*)d_in[0];
  const float* wq = (const float*)d_in[1];
  const float* wk = (const float*)d_in[2];
  const float* wv = (const float*)d_in[3];
  const float* wo = (const float*)d_in[4];
  float* out = (float*)d_out;

  char* ws = (char*)d_ws;
  const size_t MB = 1ull << 20;
  ushort* xb = (ushort*)(ws + 0);         // 8 MB; reused as Vt after gemm_qkv
  ushort* wb = (ushort*)(ws + 8 * MB);    // 8 MB: wq|wk|wv|wo bf16, contiguous
  ushort* Q  = (ushort*)(ws + 16 * MB);
  ushort* K  = (ushort*)(ws + 24 * MB);
  ushort* V  = (ushort*)(ws + 32 * MB);
  ushort* AO = (ushort*)(ws + 40 * MB);
  ushort* Vt = (ushort*)(ws + 0);
  ushort* wob = wb + 3 * 1048576;

  cvt_all<<<8192, 256, 0, stream>>>(x, wq, wk, wv, wo, xb, wb);
  gemm_qkv<<<dim3(8, 32, 3), 256, 0, stream>>>(xb, wb, Q, K, V);
  vt_kernel<<<dim3(32, 32), 256, 0, stream>>>(V, Vt);
  attn_fwd<<<1024, 256, 0, stream>>>(Q, K, Vt, AO);
  gemm_out<<<dim3(16, 32), 256, 0, stream>>>(AO, wob, out);
}